// Round 4
// baseline (406.762 us; speedup 1.0000x reference)
//
#include <hip/hip_runtime.h>

typedef unsigned int u32;

#define HW 3136

// workspace offsets (float units)
#define OFF_W7    0        // 128*49 combined dw weights (lepe BN folded)
#define OFF_BIAS  6272     // 128 folded lepe bias
#define OFF_POOL  6400     // 4*128*49
#define OFF_KEY   31488    // 4*128*49
#define OFF_AVG   56576    // 4*128 sum accumulators
#define OFF_MAXU  57088    // 4*128 max accumulators (encoded u32)
#define OFF_CA    57600    // 4*128 channel-attention sigmoid
#define OFF_VALUE 58112    // 4*128*3136
#define OFF_GATE  1663744  // 4*128*3136
#define OFF_DYN   3269376  // 4*49*3136
#define OFF_XF    3884032  // 4*128*3136
// total: 5,489,664 floats = 21.96 MB

struct Params {
  const float *x_up, *x_skip, *wq, *bq, *wk, *bk, *wv, *bv, *ww, *bw;
  const float *lk_w, *lk_s, *lk_b, *dw5, *s5, *b5, *dw3a, *s3a, *b3a,
              *dw3b, *s3b, *b3b, *dw3c, *s3c, *b3c, *lepe_s, *lepe_b;
  const float *gate_w, *gate_s, *gate_b, *fus_w, *fus_b, *ca_w1, *ca_w2, *res;
  float* W;
  float* out;
};

__device__ __forceinline__ u32 fenc(float f){
  union{float f; u32 u;} v; v.f = f;
  return (v.u & 0x80000000u) ? ~v.u : (v.u | 0x80000000u);
}
__device__ __forceinline__ float fdec(u32 u){
  union{float f; u32 uu;} v;
  v.uu = (u & 0x80000000u) ? (u ^ 0x80000000u) : ~u;
  return v.f;
}

// XCD-locality swizzle for the 784-block hot kernels: batch b owns XCD pair
// {2b, 2b+1} (blockIdx%8 round-robins across the 8 XCDs), so each batch's
// value/x_skip halo re-reads stay in a fixed pair of L2s.
__device__ __forceinline__ void swz784(int j, int& b, int& p0){
  const int xcd = j & 7;
  b = xcd >> 1;
  p0 = ((xcd & 1) + 2*(j >> 3)) * 16;   // strip 0..195 -> pixel offset
}

// ---------------------------------------------------------------------------
// K0: combined 7x7 dw weights (+folded BNs), pooled 7x7 (block mean of 8x8),
//     init channel-attention accumulators.
__global__ __launch_bounds__(256) void k_prep(Params P){
  float* W = P.W;
  const int tid = threadIdx.x, blk = blockIdx.x;
  if (blk < 32){
    const int b = blk >> 3, cg = blk & 7;
    for (int o = tid; o < 16*49; o += 256){
      const int c = cg*16 + o/49, l = o % 49;
      const int i = l/7, j = l%7;
      const float* src = P.x_up + (size_t)(b*128 + c)*HW + (i*8)*56 + j*8;
      float s = 0.f;
      #pragma unroll
      for (int di=0; di<8; ++di){
        const float4 a0 = *(const float4*)(src + di*56);
        const float4 a1 = *(const float4*)(src + di*56 + 4);
        s += a0.x+a0.y+a0.z+a0.w + a1.x+a1.y+a1.z+a1.w;
      }
      W[OFF_POOL + (size_t)(b*128+c)*49 + l] = s * (1.f/64.f);
    }
  } else {
    for (int idx = tid; idx < 128*49; idx += 256){
      const int c = idx/49, k = idx%49;
      const int dy = k/7 - 3, dx = k%7 - 3;
      float w = P.lk_s[c] * P.lk_w[c*49 + k];
      if (dy>=-2 && dy<=2 && dx>=-2 && dx<=2)
        w += P.s5[c] * P.dw5[c*25 + (dy+2)*5 + (dx+2)];
      if (dy>=-1 && dy<=1 && dx>=-1 && dx<=1)
        w += P.s3a[c] * P.dw3a[c*9 + (dy+1)*3 + (dx+1)];
      if ((dy==-2||dy==0||dy==2) && (dx==-2||dx==0||dx==2))
        w += P.s3b[c] * P.dw3b[c*9 + (dy/2+1)*3 + (dx/2+1)];
      if ((dy==-3||dy==0||dy==3) && (dx==-3||dx==0||dx==3))
        w += P.s3c[c] * P.dw3c[c*9 + (dy/3+1)*3 + (dx/3+1)];
      W[OFF_W7 + idx] = P.lepe_s[c] * w;
    }
    for (int c = tid; c < 128; c += 256){
      const float bs = P.lk_b[c] + P.b5[c] + P.b3a[c] + P.b3b[c] + P.b3c[c];
      W[OFF_BIAS + c] = P.lepe_s[c] * bs + P.lepe_b[c];
    }
    for (int i = tid; i < 512; i += 256){
      W[OFF_AVG + i] = 0.f;
      ((u32*)W + OFF_MAXU)[i] = fenc(-1e30f);
    }
  }
}

// ---------------------------------------------------------------------------
// K1: key_t[b,o,l] = bk[o] + sum_c wk[o,c]*pooled[b,c,l]. One block per (b,l).
__global__ __launch_bounds__(128) void k_key(Params P){
  __shared__ float pc[128];
  float* W = P.W;
  const int b = blockIdx.x / 49, l = blockIdx.x % 49;
  const int t = threadIdx.x;
  pc[t] = W[OFF_POOL + (size_t)(b*128+t)*49 + l];
  __syncthreads();
  float acc = P.bk[t];
  const float4* wr = (const float4*)(P.wk + t*128);
  for (int k0=0;k0<32;++k0){
    const float4 w = wr[k0];
    acc += w.x*pc[k0*4] + w.y*pc[k0*4+1] + w.z*pc[k0*4+2] + w.w*pc[k0*4+3];
  }
  W[OFF_KEY + (size_t)(b*128+t)*49 + l] = acc;
}

// ---------------------------------------------------------------------------
// K2: per-pixel pass, strip=16. Fused q/v/gate 1x1 convs (24 accumulators),
// attention over 49 pooled tokens, dynamic-weight generation.
__global__ __launch_bounds__(256) void k_main(Params P){
  __shared__ float xl[128][16];
  __shared__ float ql[128][17];
  __shared__ float st[128][17];
  __shared__ float attl[16][50];
  float* W = P.W;
  const int tid = threadIdx.x;
  int b, p0; swz784(blockIdx.x, b, p0);

  for (int idx = tid; idx < 2048; idx += 256){
    const int c = idx >> 4, px = idx & 15;
    xl[c][px] = P.x_skip[(size_t)(b*128+c)*HW + p0 + px];
  }
  __syncthreads();

  const int o = tid & 127, g = tid >> 7;
  const int pxb = g << 3;
  float aq[8], av[8], ag[8];
  {
    const float bq_ = P.bq[o], bv_ = P.bv[o];
    #pragma unroll
    for (int j=0;j<8;++j){ aq[j]=bq_; av[j]=bv_; ag[j]=0.f; }
  }
  const float4* wqr = (const float4*)(P.wq + o*128);
  const float4* wvr = (const float4*)(P.wv + o*128);
  const float4* wgr = (const float4*)(P.gate_w + o*128);
  for (int k0 = 0; k0 < 32; ++k0){
    const float4 qw = wqr[k0], vw = wvr[k0], gw = wgr[k0];
    const float qa[4] = {qw.x,qw.y,qw.z,qw.w};
    const float va[4] = {vw.x,vw.y,vw.z,vw.w};
    const float ga[4] = {gw.x,gw.y,gw.z,gw.w};
    #pragma unroll
    for (int t=0; t<4; ++t){
      const int k = k0*4 + t;
      const float4 x0 = *(const float4*)&xl[k][pxb];
      const float4 x1 = *(const float4*)&xl[k][pxb+4];
      const float xv[8] = {x0.x,x0.y,x0.z,x0.w, x1.x,x1.y,x1.z,x1.w};
      #pragma unroll
      for (int j=0;j<8;++j){
        aq[j] += qa[t] * xv[j];
        av[j] += va[t] * xv[j];
        ag[j] += ga[t] * xv[j];
      }
    }
  }
  #pragma unroll
  for (int j=0;j<8;++j){ ql[o][pxb+j] = aq[j]; st[o][pxb+j] = av[j]; }
  __syncthreads();
  for (int idx = tid; idx < 2048; idx += 256){
    const int c = idx >> 4, px = idx & 15;
    W[OFF_VALUE + (size_t)(b*128+c)*HW + p0 + px] = st[c][px];
  }
  __syncthreads();
  {
    const float gs = P.gate_s[o], gb = P.gate_b[o];
    #pragma unroll
    for (int j=0;j<8;++j){
      const float y = gs*ag[j] + gb;
      st[o][pxb+j] = y / (1.f + __expf(-y));   // SiLU
    }
  }
  __syncthreads();
  for (int idx = tid; idx < 2048; idx += 256){
    const int c = idx >> 4, px = idx & 15;
    W[OFF_GATE + (size_t)(b*128+c)*HW + p0 + px] = st[c][px];
  }
  __syncthreads();

  // ---- attention over 49 tokens: 16 lanes per pixel
  const int sub = tid & 15, px = tid >> 4;
  const float* keyb = W + OFF_KEY + (size_t)b*128*49;
  float sv[4] = {0.f,0.f,0.f,0.f};
  for (int c=0;c<128;++c){
    const float qv = ql[c][px];
    const float* kr = keyb + c*49;
    #pragma unroll
    for (int j=0;j<4;++j){
      const int l = sub + 16*j;
      if (l < 49) sv[j] += qv * kr[l];
    }
  }
  const float scale = 0.08838834764831843f;  // 128^-0.5
  float m = -1e30f;
  #pragma unroll
  for (int j=0;j<4;++j){
    const int l = sub + 16*j;
    if (l < 49){ sv[j] *= scale; m = fmaxf(m, sv[j]); }
  }
  #pragma unroll
  for (int d=1; d<16; d<<=1) m = fmaxf(m, __shfl_xor(m, d, 64));
  float ssum = 0.f;
  float ev[4];
  #pragma unroll
  for (int j=0;j<4;++j){
    const int l = sub + 16*j;
    if (l < 49){ ev[j] = __expf(sv[j] - m); ssum += ev[j]; }
  }
  #pragma unroll
  for (int d=1; d<16; d<<=1) ssum += __shfl_xor(ssum, d, 64);
  const float inv = 1.f / ssum;
  #pragma unroll
  for (int j=0;j<4;++j){
    const int l = sub + 16*j;
    if (l < 49) attl[px][l] = ev[j] * inv;
  }
  __syncthreads();
  // dyn_w = ww @ attn + bw
  #pragma unroll
  for (int j=0;j<4;++j){
    const int oo = sub + 16*j;
    if (oo < 49){
      float a = P.bw[oo];
      const float* wr = P.ww + oo*49;
      for (int l=0;l<49;++l) a += wr[l] * attl[px][l];
      W[OFF_DYN + (size_t)(b*49+oo)*HW + p0 + px] = a;
    }
  }
}

// ---------------------------------------------------------------------------
// K3: dynamic 7x7 filter on value, fus 1x1 conv, lepe dwconv, CA partials.
// strip=16: 256 threads = 16 px x 16 channel-groups of 8.
__global__ __launch_bounds__(256) void k_mix(Params P){
  __shared__ float dynl[49][16];
  __shared__ float mixl[128][17];
  float* W = P.W;
  const int tid = threadIdx.x;
  int b, p0; swz784(blockIdx.x, b, p0);
  for (int idx = tid; idx < 49*16; idx += 256){
    const int k = idx >> 4, px = idx & 15;
    dynl[k][px] = W[OFF_DYN + (size_t)(b*49+k)*HW + p0 + px];
  }
  __syncthreads();
  const int px = tid & 15, cg = tid >> 4, ch0 = cg*8;
  const int p = p0 + px, h = p / 56, w = p % 56;
  float acc[8];
  #pragma unroll
  for (int j=0;j<8;++j) acc[j]=0.f;
  const float* vbase = W + OFF_VALUE + (size_t)(b*128 + ch0)*HW;
  #pragma unroll
  for (int i=0;i<7;++i){
    const int hh = h + i - 3;
    if ((unsigned)hh >= 56u) continue;
    #pragma unroll
    for (int j=0;j<7;++j){
      const int w2 = w + j - 3;
      if ((unsigned)w2 >= 56u) continue;
      const float d = dynl[i*7+j][px];
      const float* vp = vbase + hh*56 + w2;
      #pragma unroll
      for (int cc=0;cc<8;++cc) acc[cc] += d * vp[(size_t)cc*HW];
    }
  }
  #pragma unroll
  for (int cc=0;cc<8;++cc) mixl[ch0+cc][px] = acc[cc];
  __syncthreads();
  // fus 1x1 + folded lepe bias
  float xf[8];
  #pragma unroll
  for (int cc=0;cc<8;++cc) xf[cc] = P.fus_b[ch0+cc] + W[OFF_BIAS + ch0+cc];
  for (int c=0;c<128;c+=4){
    float mv[4];
    #pragma unroll
    for (int q=0;q<4;++q) mv[q] = mixl[c+q][px];
    #pragma unroll
    for (int cc=0;cc<8;++cc){
      const float4 w4 = *(const float4*)(P.fus_w + (size_t)(ch0+cc)*128 + c);
      xf[cc] += w4.x*mv[0] + w4.y*mv[1] + w4.z*mv[2] + w4.w*mv[3];
    }
  }
  // lepe: combined 7x7 depthwise on x_skip
  const float* xb0 = P.x_skip + (size_t)(b*128 + ch0)*HW;
  const float* w7 = W + OFF_W7 + ch0*49;
  #pragma unroll
  for (int i=0;i<7;++i){
    const int hh = h + i - 3;
    if ((unsigned)hh >= 56u) continue;
    #pragma unroll
    for (int j=0;j<7;++j){
      const int w2 = w + j - 3;
      if ((unsigned)w2 >= 56u) continue;
      const int off = hh*56 + w2, k = i*7 + j;
      #pragma unroll
      for (int cc=0;cc<8;++cc)
        xf[cc] += w7[cc*49 + k] * xb0[(size_t)cc*HW + off];
    }
  }
  __syncthreads();
  #pragma unroll
  for (int cc=0;cc<8;++cc) mixl[ch0+cc][px] = xf[cc];
  __syncthreads();
  for (int idx = tid; idx < 2048; idx += 256){
    const int c = idx >> 4, pp = idx & 15;
    W[OFF_XF + (size_t)(b*128+c)*HW + p0 + pp] = mixl[c][pp];
  }
  if (tid < 128){
    float s = 0.f, mm = -1e30f;
    #pragma unroll
    for (int pp=0;pp<16;++pp){ const float v = mixl[tid][pp]; s += v; mm = fmaxf(mm, v); }
    atomicAdd(W + OFF_AVG + b*128 + tid, s);
    atomicMax((u32*)W + OFF_MAXU + b*128 + tid, fenc(mm));
  }
}

// ---------------------------------------------------------------------------
// K3b: channel-attention MLP for all 4 batches (1 block, 512 threads).
__global__ __launch_bounds__(512) void k_ca(Params P){
  __shared__ float avl[512], mxl[512], hl[64];
  float* W = P.W;
  const int tid = threadIdx.x;
  avl[tid] = W[OFF_AVG + tid] * (1.f/3136.f);
  mxl[tid] = fdec(((u32*)W + OFF_MAXU)[tid]);
  __syncthreads();
  if (tid < 64){
    const int b = tid >> 4, which = (tid >> 3) & 1, r = tid & 7;
    const float* v = (which ? mxl : avl) + b*128;
    float a = 0.f;
    const float4* wr = (const float4*)(P.ca_w1 + r*128);
    for (int k0=0;k0<32;++k0){
      const float4 w4 = wr[k0];
      a += w4.x*v[k0*4] + w4.y*v[k0*4+1] + w4.z*v[k0*4+2] + w4.w*v[k0*4+3];
    }
    hl[tid] = fmaxf(a, 0.f);
  }
  __syncthreads();
  {
    const int b = tid >> 7, c = tid & 127;
    float a = 0.f;
    #pragma unroll
    for (int r=0;r<8;++r) a += P.ca_w2[c*8+r] * (hl[b*16+r] + hl[b*16+8+r]);
    W[OFF_CA + tid] = 1.f/(1.f + __expf(-a));
  }
}

// ---------------------------------------------------------------------------
// K4: pure streaming epilogue. grid (392, 4).
__global__ __launch_bounds__(256) void k_final(Params P){
  float* W = P.W;
  const int tid = threadIdx.x;
  const int b = blockIdx.y;
  const int ofs = blockIdx.x*1024 + tid*4;
  const int c = ofs / 3136;            // 3136 % 4 == 0 -> c constant in chunk
  const size_t gi = (size_t)b*401408 + ofs;
  const float ca = W[OFF_CA + b*128 + c];
  const float res = P.res[0];
  const float4 gv = *(const float4*)(W + OFF_GATE + gi);
  const float4 xv = *(const float4*)(W + OFF_XF + gi);
  const float4 sk = *(const float4*)(P.x_skip + gi);
  float4 ov;
  ov.x = gv.x*xv.x*ca + sk.x*res;
  ov.y = gv.y*xv.y*ca + sk.y*res;
  ov.z = gv.z*xv.z*ca + sk.z*res;
  ov.w = gv.w*xv.w*ca + sk.w*res;
  *(float4*)(P.out + gi) = ov;
}

// ---------------------------------------------------------------------------
extern "C" void kernel_launch(void* const* d_in, const int* in_sizes, int n_in,
                              void* d_out, int out_size, void* d_ws, size_t ws_size,
                              hipStream_t stream){
  Params P;
  const float* const* in = (const float* const*)d_in;
  P.x_up = in[0];  P.x_skip = in[1]; P.wq = in[2];  P.bq = in[3];
  P.wk = in[4];    P.bk = in[5];     P.wv = in[6];  P.bv = in[7];
  P.ww = in[8];    P.bw = in[9];
  P.lk_w = in[10]; P.lk_s = in[11];  P.lk_b = in[12];
  P.dw5 = in[13];  P.s5 = in[14];    P.b5 = in[15];
  P.dw3a = in[16]; P.s3a = in[17];   P.b3a = in[18];
  P.dw3b = in[19]; P.s3b = in[20];   P.b3b = in[21];
  P.dw3c = in[22]; P.s3c = in[23];   P.b3c = in[24];
  P.lepe_s = in[25]; P.lepe_b = in[26];
  P.gate_w = in[27]; P.gate_s = in[28]; P.gate_b = in[29];
  P.fus_w = in[30];  P.fus_b = in[31];
  P.ca_w1 = in[32];  P.ca_w2 = in[33]; P.res = in[34];
  P.W = (float*)d_ws;
  P.out = (float*)d_out;

  hipLaunchKernelGGL(k_prep,  dim3(33),  dim3(256), 0, stream, P);
  hipLaunchKernelGGL(k_key,   dim3(196), dim3(128), 0, stream, P);
  hipLaunchKernelGGL(k_main,  dim3(784), dim3(256), 0, stream, P);
  hipLaunchKernelGGL(k_mix,   dim3(784), dim3(256), 0, stream, P);
  hipLaunchKernelGGL(k_ca,    dim3(1),   dim3(512), 0, stream, P);
  hipLaunchKernelGGL(k_final, dim3(392,4), dim3(256), 0, stream, P);
}

// Round 5
// 371.075 us; speedup vs baseline: 1.0962x; 1.0962x over previous
//
#include <hip/hip_runtime.h>

typedef unsigned int u32;

#define HW 3136
#define SCALE 0.08838834764831843f   // 128^-0.5

// workspace offsets (float units)
#define OFF_W7    0        // 128*49 combined dw weights (lepe BN folded)
#define OFF_BIAS  6272     // 128 folded lepe bias
#define OFF_POOL  6400     // 4*128*49 pooled x_up
#define OFF_MT    31488    // 4*49*128  Mt[b][l][k] = scale * sum_c wq[c,k]*key[b,c,l]
#define OFF_D     56576    // 4*49      d[b][l]    = scale * sum_c bq[c]*key[b,c,l]
#define OFF_AVG   56772    // 4*128 sum accumulators
#define OFF_MAXU  57284    // 4*128 max accumulators (encoded u32)
#define OFF_CA    57796    // 4*128 channel-attention sigmoid
#define OFF_VALUE 58308    // 4*128*3136
#define OFF_GATE  1663940  // 4*128*3136
#define OFF_DYN   3269572  // 4*49*3136
#define OFF_XF    3884228  // 4*128*3136
// total 5,489,860 floats = 21.96 MB

struct Params {
  const float *x_up, *x_skip, *wq, *bq, *wk, *bk, *wv, *bv, *ww, *bw;
  const float *lk_w, *lk_s, *lk_b, *dw5, *s5, *b5, *dw3a, *s3a, *b3a,
              *dw3b, *s3b, *b3b, *dw3c, *s3c, *b3c, *lepe_s, *lepe_b;
  const float *gate_w, *gate_s, *gate_b, *fus_w, *fus_b, *ca_w1, *ca_w2, *res;
  float* W;
  float* out;
};

__device__ __forceinline__ u32 fenc(float f){
  union{float f; u32 u;} v; v.f = f;
  return (v.u & 0x80000000u) ? ~v.u : (v.u | 0x80000000u);
}
__device__ __forceinline__ float fdec(u32 u){
  union{float f; u32 uu;} v;
  v.uu = (u & 0x80000000u) ? (u ^ 0x80000000u) : ~u;
  return v.f;
}

// XCD-locality swizzle, 784 blocks -> (batch, strip16): batch b owns XCD pair
// {2b,2b+1} (blockIdx%8 is the XCD round-robin), so each batch's workspace
// tensors stay resident in a fixed pair of L2s across producer/consumer kernels.
__device__ __forceinline__ void swz784(int j, int& b, int& p0){
  const int xcd = j & 7;
  b = xcd >> 1;
  p0 = ((xcd & 1) + 2*(j >> 3)) * 16;
}

// ---------------------------------------------------------------------------
// K0: pooled 7x7 (block mean of 8x8) + combined 7x7 dw weights (+folded BNs)
//     + init channel-attention accumulators.
__global__ __launch_bounds__(256) void k_prep(Params P){
  float* W = P.W;
  const int tid = threadIdx.x, blk = blockIdx.x;
  if (blk < 32){
    const int b = blk >> 3, cg = blk & 7;
    for (int o = tid; o < 16*49; o += 256){
      const int c = cg*16 + o/49, l = o % 49;
      const int i = l/7, j = l%7;
      const float* src = P.x_up + (size_t)(b*128 + c)*HW + (i*8)*56 + j*8;
      float s = 0.f;
      #pragma unroll
      for (int di=0; di<8; ++di){
        const float4 a0 = *(const float4*)(src + di*56);
        const float4 a1 = *(const float4*)(src + di*56 + 4);
        s += a0.x+a0.y+a0.z+a0.w + a1.x+a1.y+a1.z+a1.w;
      }
      W[OFF_POOL + (size_t)(b*128+c)*49 + l] = s * (1.f/64.f);
    }
  } else {
    for (int idx = tid; idx < 128*49; idx += 256){
      const int c = idx/49, k = idx%49;
      const int dy = k/7 - 3, dx = k%7 - 3;
      float w = P.lk_s[c] * P.lk_w[c*49 + k];
      if (dy>=-2 && dy<=2 && dx>=-2 && dx<=2)
        w += P.s5[c] * P.dw5[c*25 + (dy+2)*5 + (dx+2)];
      if (dy>=-1 && dy<=1 && dx>=-1 && dx<=1)
        w += P.s3a[c] * P.dw3a[c*9 + (dy+1)*3 + (dx+1)];
      if ((dy==-2||dy==0||dy==2) && (dx==-2||dx==0||dx==2))
        w += P.s3b[c] * P.dw3b[c*9 + (dy/2+1)*3 + (dx/2+1)];
      if ((dy==-3||dy==0||dy==3) && (dx==-3||dx==0||dx==3))
        w += P.s3c[c] * P.dw3c[c*9 + (dy/3+1)*3 + (dx/3+1)];
      W[OFF_W7 + idx] = P.lepe_s[c] * w;
    }
    for (int c = tid; c < 128; c += 256){
      const float bs = P.lk_b[c] + P.b5[c] + P.b3a[c] + P.b3b[c] + P.b3c[c];
      W[OFF_BIAS + c] = P.lepe_s[c] * bs + P.lepe_b[c];
    }
    for (int i = tid; i < 512; i += 256){
      W[OFF_AVG + i] = 0.f;
      ((u32*)W + OFF_MAXU)[i] = fenc(-1e30f);
    }
  }
}

// ---------------------------------------------------------------------------
// K1: per (b,l): key col -> Mt[b][l][k] (scaled) and d[b][l] (scaled).
// Mt[k,l] = sum_c wq[c,k]*key[c,l]; attention logits become x^T * Mt + d,
// eliminating the query GEMM entirely.
__global__ __launch_bounds__(128) void k_key(Params P){
  __shared__ float pc[128], kc[128], red[128];
  float* W = P.W;
  const int b = blockIdx.x / 49, l = blockIdx.x % 49;
  const int t = threadIdx.x;
  pc[t] = W[OFF_POOL + (size_t)(b*128+t)*49 + l];
  __syncthreads();
  float acc = P.bk[t];
  const float4* wr = (const float4*)(P.wk + t*128);
  #pragma unroll 8
  for (int k0=0;k0<32;++k0){
    const float4 w = wr[k0];
    acc += w.x*pc[k0*4] + w.y*pc[k0*4+1] + w.z*pc[k0*4+2] + w.w*pc[k0*4+3];
  }
  kc[t] = acc;
  red[t] = P.bq[t] * acc;
  __syncthreads();
  float m = 0.f;
  #pragma unroll 8
  for (int c=0;c<128;++c) m += P.wq[c*128 + t] * kc[c];   // lanes coalesce over t
  W[OFF_MT + (size_t)(b*49+l)*128 + t] = m * SCALE;
  if (t < 64) red[t] += red[t+64];
  __syncthreads();
  if (t < 32) red[t] += red[t+32];
  __syncthreads();
  if (t < 16) red[t] += red[t+16];
  __syncthreads();
  if (t < 8) red[t] += red[t+8];
  __syncthreads();
  if (t < 4) red[t] += red[t+4];
  __syncthreads();
  if (t == 0) W[OFF_D + b*49 + l] = (red[0]+red[1]+red[2]+red[3]) * SCALE;
}

// ---------------------------------------------------------------------------
// K2: v / gate 1x1 convs. grid (784, 2): x = (b,strip16) swizzled, y = chunk.
// Thread = 2 outs x 4 px, k-loop with register-double-buffered weight prefetch.
__global__ __launch_bounds__(256) void k_gemm(Params P){
  __shared__ float xl[128][16];
  float* W = P.W;
  const int tid = threadIdx.x;
  int b, p0; swz784(blockIdx.x, b, p0);
  const int chunk = blockIdx.y;
  const float* __restrict__ wmat = chunk ? P.gate_w : P.wv;

  for (int idx = tid; idx < 2048; idx += 256){
    const int c = idx >> 4, px = idx & 15;
    xl[c][px] = P.x_skip[(size_t)(b*128+c)*HW + p0 + px];
  }
  __syncthreads();

  const int pq = tid & 3, oq = tid >> 2;     // 4 px-quads x 64 out-pairs
  const int o0 = oq*2;
  const float* __restrict__ wr0 = wmat + (size_t)o0*128;
  const float* __restrict__ wr1 = wmat + (size_t)(o0+1)*128;
  float4 a0 = {0.f,0.f,0.f,0.f}, a1 = {0.f,0.f,0.f,0.f};
  float4 wb0 = *(const float4*)(wr0);
  float4 wb1 = *(const float4*)(wr1);
  for (int g=0; g<32; ++g){
    const float4 wc0 = wb0, wc1 = wb1;
    if (g < 31){
      wb0 = *(const float4*)(wr0 + (g+1)*4);
      wb1 = *(const float4*)(wr1 + (g+1)*4);
    }
    #pragma unroll
    for (int kk=0; kk<4; ++kk){
      const float4 x4 = *(const float4*)&xl[g*4+kk][pq*4];
      const float w0 = kk==0 ? wc0.x : kk==1 ? wc0.y : kk==2 ? wc0.z : wc0.w;
      const float w1 = kk==0 ? wc1.x : kk==1 ? wc1.y : kk==2 ? wc1.z : wc1.w;
      a0.x += w0*x4.x; a0.y += w0*x4.y; a0.z += w0*x4.z; a0.w += w0*x4.w;
      a1.x += w1*x4.x; a1.y += w1*x4.y; a1.z += w1*x4.z; a1.w += w1*x4.w;
    }
  }
  if (chunk == 0){
    const float b0 = P.bv[o0], b1 = P.bv[o0+1];
    float4 r0 = {a0.x+b0, a0.y+b0, a0.z+b0, a0.w+b0};
    float4 r1 = {a1.x+b1, a1.y+b1, a1.z+b1, a1.w+b1};
    *(float4*)(W + OFF_VALUE + (size_t)(b*128+o0  )*HW + p0 + pq*4) = r0;
    *(float4*)(W + OFF_VALUE + (size_t)(b*128+o0+1)*HW + p0 + pq*4) = r1;
  } else {
    const float s0 = P.gate_s[o0], s1 = P.gate_s[o0+1];
    const float c0 = P.gate_b[o0], c1 = P.gate_b[o0+1];
    float y[8] = {s0*a0.x+c0, s0*a0.y+c0, s0*a0.z+c0, s0*a0.w+c0,
                  s1*a1.x+c1, s1*a1.y+c1, s1*a1.z+c1, s1*a1.w+c1};
    #pragma unroll
    for (int q=0;q<8;++q) y[q] = y[q] / (1.f + __expf(-y[q]));
    float4 r0 = {y[0],y[1],y[2],y[3]}, r1 = {y[4],y[5],y[6],y[7]};
    *(float4*)(W + OFF_GATE + (size_t)(b*128+o0  )*HW + p0 + pq*4) = r0;
    *(float4*)(W + OFF_GATE + (size_t)(b*128+o0+1)*HW + p0 + pq*4) = r1;
  }
}

// ---------------------------------------------------------------------------
// K3: attention logits (x^T Mt + d), softmax, dyn_w = ww@attn + bw.
// grid 784 (b,strip16 swizzled). Thread = (px 0..15, sub 0..15).
__global__ __launch_bounds__(256) void k_attn(Params P){
  __shared__ float xl[128][16];
  __shared__ float attl[16][52];
  float* W = P.W;
  const int tid = threadIdx.x;
  int b, p0; swz784(blockIdx.x, b, p0);

  for (int idx = tid; idx < 2048; idx += 256){
    const int c = idx >> 4, px = idx & 15;
    xl[c][px] = P.x_skip[(size_t)(b*128+c)*HW + p0 + px];
  }
  __syncthreads();

  const int px = tid >> 4, sub = tid & 15;
  const int l0 = sub, l1 = sub+16, l2 = sub+32, l3 = sub+48;   // l3 valid only sub==0
  const float* __restrict__ mt = W + OFF_MT + (size_t)b*49*128;
  const float* __restrict__ dv = W + OFF_D + b*49;
  float lv0 = dv[l0], lv1 = dv[l1], lv2 = dv[l2];
  float lv3 = (l3 < 49) ? dv[l3] : -1e30f;
  float a3 = 0.f;
  #pragma unroll 2
  for (int g=0; g<32; ++g){
    const float4 m0 = *(const float4*)(mt + (size_t)l0*128 + g*4);
    const float4 m1 = *(const float4*)(mt + (size_t)l1*128 + g*4);
    const float4 m2 = *(const float4*)(mt + (size_t)l2*128 + g*4);
    float4 m3 = {0.f,0.f,0.f,0.f};
    if (l3 < 49) m3 = *(const float4*)(mt + (size_t)l3*128 + g*4);
    const float x0 = xl[g*4+0][px], x1 = xl[g*4+1][px],
                x2 = xl[g*4+2][px], x3 = xl[g*4+3][px];
    lv0 += m0.x*x0 + m0.y*x1 + m0.z*x2 + m0.w*x3;
    lv1 += m1.x*x0 + m1.y*x1 + m1.z*x2 + m1.w*x3;
    lv2 += m2.x*x0 + m2.y*x1 + m2.z*x2 + m2.w*x3;
    a3  += m3.x*x0 + m3.y*x1 + m3.z*x2 + m3.w*x3;
  }
  if (l3 < 49) lv3 += a3;

  float m = fmaxf(fmaxf(lv0, lv1), fmaxf(lv2, lv3));
  #pragma unroll
  for (int d=1; d<16; d<<=1) m = fmaxf(m, __shfl_xor(m, d, 64));
  const float e0 = __expf(lv0-m), e1 = __expf(lv1-m), e2 = __expf(lv2-m);
  const float e3 = (l3 < 49) ? __expf(lv3-m) : 0.f;
  float s = e0+e1+e2+e3;
  #pragma unroll
  for (int d=1; d<16; d<<=1) s += __shfl_xor(s, d, 64);
  const float inv = 1.f / s;
  attl[px][l0] = e0*inv;
  attl[px][l1] = e1*inv;
  attl[px][l2] = e2*inv;
  if (l3 < 49) attl[px][l3] = e3*inv;
  __syncthreads();

  // dyn_w
  #pragma unroll
  for (int j=0;j<4;++j){
    const int oo = sub + 16*j;
    if (oo < 49){
      float a = P.bw[oo];
      const float* __restrict__ wr = P.ww + oo*49;
      #pragma unroll 7
      for (int l=0;l<49;++l) a += wr[l] * attl[px][l];
      W[OFF_DYN + (size_t)(b*49+oo)*HW + p0 + px] = a;
    }
  }
}

// ---------------------------------------------------------------------------
// K4: dynamic 7x7 filter on value, fus 1x1 conv, lepe dwconv, CA partials.
// strip=16: 256 threads = 16 px x 16 channel-groups of 8. (unchanged from r4)
__global__ __launch_bounds__(256) void k_mix(Params P){
  __shared__ float dynl[49][16];
  __shared__ float mixl[128][17];
  float* W = P.W;
  const int tid = threadIdx.x;
  int b, p0; swz784(blockIdx.x, b, p0);
  for (int idx = tid; idx < 49*16; idx += 256){
    const int k = idx >> 4, px = idx & 15;
    dynl[k][px] = W[OFF_DYN + (size_t)(b*49+k)*HW + p0 + px];
  }
  __syncthreads();
  const int px = tid & 15, cg = tid >> 4, ch0 = cg*8;
  const int p = p0 + px, h = p / 56, w = p % 56;
  float acc[8];
  #pragma unroll
  for (int j=0;j<8;++j) acc[j]=0.f;
  const float* vbase = W + OFF_VALUE + (size_t)(b*128 + ch0)*HW;
  #pragma unroll
  for (int i=0;i<7;++i){
    const int hh = h + i - 3;
    if ((unsigned)hh >= 56u) continue;
    #pragma unroll
    for (int j=0;j<7;++j){
      const int w2 = w + j - 3;
      if ((unsigned)w2 >= 56u) continue;
      const float d = dynl[i*7+j][px];
      const float* vp = vbase + hh*56 + w2;
      #pragma unroll
      for (int cc=0;cc<8;++cc) acc[cc] += d * vp[(size_t)cc*HW];
    }
  }
  #pragma unroll
  for (int cc=0;cc<8;++cc) mixl[ch0+cc][px] = acc[cc];
  __syncthreads();
  float xf[8];
  #pragma unroll
  for (int cc=0;cc<8;++cc) xf[cc] = P.fus_b[ch0+cc] + W[OFF_BIAS + ch0+cc];
  for (int c=0;c<128;c+=4){
    float mv[4];
    #pragma unroll
    for (int q=0;q<4;++q) mv[q] = mixl[c+q][px];
    #pragma unroll
    for (int cc=0;cc<8;++cc){
      const float4 w4 = *(const float4*)(P.fus_w + (size_t)(ch0+cc)*128 + c);
      xf[cc] += w4.x*mv[0] + w4.y*mv[1] + w4.z*mv[2] + w4.w*mv[3];
    }
  }
  const float* xb0 = P.x_skip + (size_t)(b*128 + ch0)*HW;
  const float* w7 = W + OFF_W7 + ch0*49;
  #pragma unroll
  for (int i=0;i<7;++i){
    const int hh = h + i - 3;
    if ((unsigned)hh >= 56u) continue;
    #pragma unroll
    for (int j=0;j<7;++j){
      const int w2 = w + j - 3;
      if ((unsigned)w2 >= 56u) continue;
      const int off = hh*56 + w2, k = i*7 + j;
      #pragma unroll
      for (int cc=0;cc<8;++cc)
        xf[cc] += w7[cc*49 + k] * xb0[(size_t)cc*HW + off];
    }
  }
  __syncthreads();
  #pragma unroll
  for (int cc=0;cc<8;++cc) mixl[ch0+cc][px] = xf[cc];
  __syncthreads();
  for (int idx = tid; idx < 2048; idx += 256){
    const int c = idx >> 4, pp = idx & 15;
    W[OFF_XF + (size_t)(b*128+c)*HW + p0 + pp] = mixl[c][pp];
  }
  if (tid < 128){
    float s = 0.f, mm = -1e30f;
    #pragma unroll
    for (int pp=0;pp<16;++pp){ const float v = mixl[tid][pp]; s += v; mm = fmaxf(mm, v); }
    atomicAdd(W + OFF_AVG + b*128 + tid, s);
    atomicMax((u32*)W + OFF_MAXU + b*128 + tid, fenc(mm));
  }
}

// ---------------------------------------------------------------------------
// K5: channel-attention MLP for all 4 batches (1 block, 512 threads).
__global__ __launch_bounds__(512) void k_ca(Params P){
  __shared__ float avl[512], mxl[512], hl[64];
  float* W = P.W;
  const int tid = threadIdx.x;
  avl[tid] = W[OFF_AVG + tid] * (1.f/3136.f);
  mxl[tid] = fdec(((u32*)W + OFF_MAXU)[tid]);
  __syncthreads();
  if (tid < 64){
    const int b = tid >> 4, which = (tid >> 3) & 1, r = tid & 7;
    const float* v = (which ? mxl : avl) + b*128;
    float a = 0.f;
    const float4* wr = (const float4*)(P.ca_w1 + r*128);
    for (int k0=0;k0<32;++k0){
      const float4 w4 = wr[k0];
      a += w4.x*v[k0*4] + w4.y*v[k0*4+1] + w4.z*v[k0*4+2] + w4.w*v[k0*4+3];
    }
    hl[tid] = fmaxf(a, 0.f);
  }
  __syncthreads();
  {
    const int b = tid >> 7, c = tid & 127;
    float a = 0.f;
    #pragma unroll
    for (int r=0;r<8;++r) a += P.ca_w2[c*8+r] * (hl[b*16+r] + hl[b*16+8+r]);
    W[OFF_CA + tid] = 1.f/(1.f + __expf(-a));
  }
}

// ---------------------------------------------------------------------------
// K6: pure streaming epilogue. grid (392, 4).
__global__ __launch_bounds__(256) void k_final(Params P){
  float* W = P.W;
  const int tid = threadIdx.x;
  const int b = blockIdx.y;
  const int ofs = blockIdx.x*1024 + tid*4;
  const int c = ofs / 3136;            // 3136 % 4 == 0 -> c constant in chunk
  const size_t gi = (size_t)b*401408 + ofs;
  const float ca = W[OFF_CA + b*128 + c];
  const float res = P.res[0];
  const float4 gv = *(const float4*)(W + OFF_GATE + gi);
  const float4 xv = *(const float4*)(W + OFF_XF + gi);
  const float4 sk = *(const float4*)(P.x_skip + gi);
  float4 ov;
  ov.x = gv.x*xv.x*ca + sk.x*res;
  ov.y = gv.y*xv.y*ca + sk.y*res;
  ov.z = gv.z*xv.z*ca + sk.z*res;
  ov.w = gv.w*xv.w*ca + sk.w*res;
  *(float4*)(P.out + gi) = ov;
}

// ---------------------------------------------------------------------------
extern "C" void kernel_launch(void* const* d_in, const int* in_sizes, int n_in,
                              void* d_out, int out_size, void* d_ws, size_t ws_size,
                              hipStream_t stream){
  Params P;
  const float* const* in = (const float* const*)d_in;
  P.x_up = in[0];  P.x_skip = in[1]; P.wq = in[2];  P.bq = in[3];
  P.wk = in[4];    P.bk = in[5];     P.wv = in[6];  P.bv = in[7];
  P.ww = in[8];    P.bw = in[9];
  P.lk_w = in[10]; P.lk_s = in[11];  P.lk_b = in[12];
  P.dw5 = in[13];  P.s5 = in[14];    P.b5 = in[15];
  P.dw3a = in[16]; P.s3a = in[17];   P.b3a = in[18];
  P.dw3b = in[19]; P.s3b = in[20];   P.b3b = in[21];
  P.dw3c = in[22]; P.s3c = in[23];   P.b3c = in[24];
  P.lepe_s = in[25]; P.lepe_b = in[26];
  P.gate_w = in[27]; P.gate_s = in[28]; P.gate_b = in[29];
  P.fus_w = in[30];  P.fus_b = in[31];
  P.ca_w1 = in[32];  P.ca_w2 = in[33]; P.res = in[34];
  P.W = (float*)d_ws;
  P.out = (float*)d_out;

  hipLaunchKernelGGL(k_prep,  dim3(33),    dim3(256), 0, stream, P);
  hipLaunchKernelGGL(k_key,   dim3(196),   dim3(128), 0, stream, P);
  hipLaunchKernelGGL(k_gemm,  dim3(784,2), dim3(256), 0, stream, P);
  hipLaunchKernelGGL(k_attn,  dim3(784),   dim3(256), 0, stream, P);
  hipLaunchKernelGGL(k_mix,   dim3(784),   dim3(256), 0, stream, P);
  hipLaunchKernelGGL(k_ca,    dim3(1),     dim3(512), 0, stream, P);
  hipLaunchKernelGGL(k_final, dim3(392,4), dim3(256), 0, stream, P);
}

// Round 6
// 283.999 us; speedup vs baseline: 1.4323x; 1.3066x over previous
//
#include <hip/hip_runtime.h>

typedef unsigned int u32;

#define HW 3136
#define SCALE 0.08838834764831843f   // 128^-0.5

// workspace offsets (float units)
#define OFF_W7    0        // 128*49 combined dw weights (lepe BN folded)
#define OFF_BIAS  6272     // 128: lepe folded bias + fus_b
#define OFF_POOL  6400     // 4*128*49 pooled x_up
#define OFF_MT    31488    // 4*128*49, TRANSPOSED: Mt[b][k][l]
#define OFF_D     56576    // 4*49
#define OFF_AVG   56772    // 4*128
#define OFF_MAXU  57284    // 4*128 (encoded u32)
#define OFF_CA    57796    // 4*128
#define OFF_WC    58308    // 128*128 combined fus_w @ wv
#define OFF_BC    74692    // 128 combined fus_w @ bv
#define OFF_FV    74820    // 4*128*3136  fv = fus(value)
#define OFF_GATE  1680452  // 4*128*3136
#define OFF_DYN   3286084  // 4*49*3136
#define OFF_XF    3900740  // 4*128*3136
// total 5,506,372 floats = 22.03 MB

struct Params {
  const float *x_up, *x_skip, *wq, *bq, *wk, *bk, *wv, *bv, *ww, *bw;
  const float *lk_w, *lk_s, *lk_b, *dw5, *s5, *b5, *dw3a, *s3a, *b3a,
              *dw3b, *s3b, *b3b, *dw3c, *s3c, *b3c, *lepe_s, *lepe_b;
  const float *gate_w, *gate_s, *gate_b, *fus_w, *fus_b, *ca_w1, *ca_w2, *res;
  float* W;
  float* out;
};

__device__ __forceinline__ u32 fenc(float f){
  union{float f; u32 u;} v; v.f = f;
  return (v.u & 0x80000000u) ? ~v.u : (v.u | 0x80000000u);
}
__device__ __forceinline__ float fdec(u32 u){
  union{float f; u32 uu;} v;
  v.uu = (u & 0x80000000u) ? (u ^ 0x80000000u) : ~u;
  return v.f;
}

// ---------------------------------------------------------------------------
// K0 (grid 194): [0,128) pooling; 128: W7/bias/init; [129,193): Wc; 193: bc.
__global__ __launch_bounds__(256) void k_prep(Params P){
  float* W = P.W;
  const int tid = threadIdx.x, blk = blockIdx.x;
  if (blk < 128){
    const int b = blk >> 5, c0 = (blk & 31) * 4;
    if (tid < 196){
      const int ci = tid / 49, l = tid % 49;
      const int c = c0 + ci, i = l / 7, j = l % 7;
      const float* src = P.x_up + (size_t)(b*128 + c)*HW + (i*8)*56 + j*8;
      float s = 0.f;
      #pragma unroll
      for (int di=0; di<8; ++di){
        const float4 a0 = *(const float4*)(src + di*56);
        const float4 a1 = *(const float4*)(src + di*56 + 4);
        s += a0.x+a0.y+a0.z+a0.w + a1.x+a1.y+a1.z+a1.w;
      }
      W[OFF_POOL + (size_t)(b*128+c)*49 + l] = s * (1.f/64.f);
    }
  } else if (blk == 128){
    for (int idx = tid; idx < 6272; idx += 256){
      const int c = idx/49, k = idx%49;
      const int dy = k/7 - 3, dx = k%7 - 3;
      float w = P.lk_s[c] * P.lk_w[c*49 + k];
      if (dy>=-2 && dy<=2 && dx>=-2 && dx<=2)
        w += P.s5[c] * P.dw5[c*25 + (dy+2)*5 + (dx+2)];
      if (dy>=-1 && dy<=1 && dx>=-1 && dx<=1)
        w += P.s3a[c] * P.dw3a[c*9 + (dy+1)*3 + (dx+1)];
      if ((dy==-2||dy==0||dy==2) && (dx==-2||dx==0||dx==2))
        w += P.s3b[c] * P.dw3b[c*9 + (dy/2+1)*3 + (dx/2+1)];
      if ((dy==-3||dy==0||dy==3) && (dx==-3||dx==0||dx==3))
        w += P.s3c[c] * P.dw3c[c*9 + (dy/3+1)*3 + (dx/3+1)];
      W[OFF_W7 + idx] = P.lepe_s[c] * w;
    }
    if (tid < 128){
      const float bs = P.lk_b[tid] + P.b5[tid] + P.b3a[tid] + P.b3b[tid] + P.b3c[tid];
      W[OFF_BIAS + tid] = P.lepe_s[tid] * bs + P.lepe_b[tid] + P.fus_b[tid];
    }
    for (int i = tid; i < 512; i += 256){
      W[OFF_AVG + i] = 0.f;
      ((u32*)W + OFF_MAXU)[i] = fenc(-1e30f);
    }
  } else if (blk < 193){
    const int o = (blk - 129)*2 + (tid >> 7), c = tid & 127;
    float a = 0.f;
    #pragma unroll 8
    for (int m=0;m<128;++m) a += P.fus_w[o*128+m] * P.wv[m*128+c];
    W[OFF_WC + o*128 + c] = a;
  } else {
    if (tid < 128){
      float a = 0.f;
      #pragma unroll 8
      for (int m=0;m<128;++m) a += P.fus_w[tid*128+m] * P.bv[m];
      W[OFF_BC + tid] = a;
    }
  }
}

// ---------------------------------------------------------------------------
// K1 (196 blocks x 128): key col -> Mt[b][k][l] (transposed, scaled), D[b][l].
__global__ __launch_bounds__(128) void k_key(Params P){
  __shared__ float pc[128], kc[128], red[128];
  float* W = P.W;
  const int b = blockIdx.x / 49, l = blockIdx.x % 49;
  const int t = threadIdx.x;
  pc[t] = W[OFF_POOL + (size_t)(b*128+t)*49 + l];
  __syncthreads();
  float acc = P.bk[t];
  const float4* wr = (const float4*)(P.wk + t*128);
  #pragma unroll 8
  for (int k0=0;k0<32;++k0){
    const float4 w = wr[k0];
    acc += w.x*pc[k0*4] + w.y*pc[k0*4+1] + w.z*pc[k0*4+2] + w.w*pc[k0*4+3];
  }
  kc[t] = acc;
  red[t] = P.bq[t] * acc;
  __syncthreads();
  float m = 0.f;
  #pragma unroll 8
  for (int c=0;c<128;++c) m += P.wq[c*128 + t] * kc[c];
  W[OFF_MT + (size_t)b*6272 + t*49 + l] = m * SCALE;   // [k=t][l]
  if (t < 64) red[t] += red[t+64];
  __syncthreads();
  if (t < 32) red[t] += red[t+32];
  __syncthreads();
  if (t < 16) red[t] += red[t+16];
  __syncthreads();
  if (t < 8) red[t] += red[t+8];
  __syncthreads();
  if (t < 4) red[t] += red[t+4];
  __syncthreads();
  if (t == 0) W[OFF_D + b*49 + l] = (red[0]+red[1]+red[2]+red[3]) * SCALE;
}

// ---------------------------------------------------------------------------
// K2: fv / gate 1x1 conv, grid (392,2). Block: strip32 x all 128 outs.
// Weights staged in LDS in 4 k-chunks; inner loop pure LDS+FMA.
__global__ __launch_bounds__(256, 4) void k_gemm(Params P){
  __shared__ float xl[128][36];    // stride 36: 16B-aligned rows, staggered banks
  __shared__ float wl[32][132];    // [k][o] transposed chunk
  float* W = P.W;
  const int tid = threadIdx.x;
  const int x = blockIdx.x, xcd = x & 7;
  const int b = xcd >> 1;
  const int p0 = ((xcd & 1) + 2*(x >> 3)) * 32;
  const int mat = blockIdx.y;
  const float* __restrict__ wsrc = mat ? P.gate_w : (W + OFF_WC);

  for (int idx = tid; idx < 1024; idx += 256){
    const int c = idx >> 3, pq = idx & 7;
    *(float4*)&xl[c][pq*4] =
        *(const float4*)(P.x_skip + (size_t)(b*128+c)*HW + p0 + pq*4);
  }

  const int oq = tid >> 2, pq = tid & 3;
  const int o0 = oq*2, px = pq*8;
  float i0 = 0.f, i1 = 0.f;
  if (mat == 0){ i0 = W[OFF_BC + o0]; i1 = W[OFF_BC + o0 + 1]; }
  float a0[8], a1[8];
  #pragma unroll
  for (int j=0;j<8;++j){ a0[j]=i0; a1[j]=i1; }

  for (int g=0; g<4; ++g){
    __syncthreads();
    for (int idx = tid; idx < 1024; idx += 256){
      const int o = idx >> 3, kq = idx & 7;
      const float4 v = *(const float4*)(wsrc + (size_t)o*128 + g*32 + kq*4);
      wl[kq*4+0][o] = v.x; wl[kq*4+1][o] = v.y;
      wl[kq*4+2][o] = v.z; wl[kq*4+3][o] = v.w;
    }
    __syncthreads();
    #pragma unroll 8
    for (int k=0;k<32;++k){
      const float2 w2 = *(const float2*)&wl[k][o0];
      const float4 xa = *(const float4*)&xl[g*32+k][px];
      const float4 xb = *(const float4*)&xl[g*32+k][px+4];
      const float xv[8] = {xa.x,xa.y,xa.z,xa.w, xb.x,xb.y,xb.z,xb.w};
      #pragma unroll
      for (int j=0;j<8;++j){ a0[j] += w2.x*xv[j]; a1[j] += w2.y*xv[j]; }
    }
  }
  if (mat == 0){
    float* d0 = W + OFF_FV + (size_t)(b*128 + o0)*HW + p0 + px;
    float* d1 = W + OFF_FV + (size_t)(b*128 + o0 + 1)*HW + p0 + px;
    float4 v;
    v.x=a0[0];v.y=a0[1];v.z=a0[2];v.w=a0[3]; *(float4*)d0 = v;
    v.x=a0[4];v.y=a0[5];v.z=a0[6];v.w=a0[7]; *(float4*)(d0+4) = v;
    v.x=a1[0];v.y=a1[1];v.z=a1[2];v.w=a1[3]; *(float4*)d1 = v;
    v.x=a1[4];v.y=a1[5];v.z=a1[6];v.w=a1[7]; *(float4*)(d1+4) = v;
  } else {
    const float s0 = P.gate_s[o0], s1 = P.gate_s[o0+1];
    const float c0 = P.gate_b[o0], c1 = P.gate_b[o0+1];
    #pragma unroll
    for (int j=0;j<8;++j){
      float y0 = s0*a0[j] + c0, y1 = s1*a1[j] + c1;
      a0[j] = y0 / (1.f + __expf(-y0));
      a1[j] = y1 / (1.f + __expf(-y1));
    }
    float* d0 = W + OFF_GATE + (size_t)(b*128 + o0)*HW + p0 + px;
    float* d1 = W + OFF_GATE + (size_t)(b*128 + o0 + 1)*HW + p0 + px;
    float4 v;
    v.x=a0[0];v.y=a0[1];v.z=a0[2];v.w=a0[3]; *(float4*)d0 = v;
    v.x=a0[4];v.y=a0[5];v.z=a0[6];v.w=a0[7]; *(float4*)(d0+4) = v;
    v.x=a1[0];v.y=a1[1];v.z=a1[2];v.w=a1[3]; *(float4*)d1 = v;
    v.x=a1[4];v.y=a1[5];v.z=a1[6];v.w=a1[7]; *(float4*)(d1+4) = v;
  }
}

// ---------------------------------------------------------------------------
// K3 (784 blocks): logits = x^T Mt + D (all-LDS), softmax, dyn = ww@attn + bw.
__global__ __launch_bounds__(256, 3) void k_attn(Params P){
  __shared__ float xl[128][16];
  __shared__ float mtl[128][52];
  __shared__ float wwl[49][52];
  __shared__ float attl[16][52];
  __shared__ float dvl[52];
  float* W = P.W;
  const int tid = threadIdx.x;
  const int x = blockIdx.x, xcd = x & 7;
  const int b = xcd >> 1;
  const int p0 = ((xcd & 1) + 2*(x >> 3)) * 16;

  for (int idx = tid; idx < 512; idx += 256){
    const int c = idx >> 2, pq = idx & 3;
    *(float4*)&xl[c][pq*4] =
        *(const float4*)(P.x_skip + (size_t)(b*128+c)*HW + p0 + pq*4);
  }
  for (int idx = tid; idx < 6272; idx += 256)
    mtl[idx/49][idx%49] = W[OFF_MT + (size_t)b*6272 + idx];
  for (int idx = tid; idx < 2401; idx += 256)
    wwl[idx/49][idx%49] = P.ww[idx];
  if (tid < 49) dvl[tid] = W[OFF_D + b*49 + tid];
  __syncthreads();

  const int px = tid >> 4, sub = tid & 15;
  const int l0 = sub, l1 = sub+16, l2 = sub+32, l3 = sub+48;
  const int l3c = (l3 < 49) ? l3 : 51;     // clamped; garbage discarded
  float lv0 = dvl[l0], lv1 = dvl[l1], lv2 = dvl[l2];
  float lv3 = (l3 < 49) ? dvl[l3] : -1e30f;
  float a3 = 0.f;
  #pragma unroll 4
  for (int c=0;c<128;++c){
    const float xv = xl[c][px];
    lv0 += mtl[c][l0]*xv;
    lv1 += mtl[c][l1]*xv;
    lv2 += mtl[c][l2]*xv;
    a3  += mtl[c][l3c]*xv;
  }
  if (l3 < 49) lv3 += a3;

  float m = fmaxf(fmaxf(lv0, lv1), fmaxf(lv2, lv3));
  #pragma unroll
  for (int d=1; d<16; d<<=1) m = fmaxf(m, __shfl_xor(m, d, 64));
  const float e0 = __expf(lv0-m), e1 = __expf(lv1-m), e2 = __expf(lv2-m);
  const float e3 = (l3 < 49) ? __expf(lv3-m) : 0.f;
  float s = e0+e1+e2+e3;
  #pragma unroll
  for (int d=1; d<16; d<<=1) s += __shfl_xor(s, d, 64);
  const float inv = 1.f / s;
  attl[px][l0] = e0*inv;
  attl[px][l1] = e1*inv;
  attl[px][l2] = e2*inv;
  if (l3 < 49) attl[px][l3] = e3*inv;
  __syncthreads();

  #pragma unroll
  for (int j=0;j<4;++j){
    const int oo = sub + 16*j;
    if (oo < 49){
      float a = P.bw[oo];
      #pragma unroll 7
      for (int l=0;l<49;++l) a += wwl[oo][l] * attl[px][l];
      W[OFF_DYN + (size_t)(b*49+oo)*HW + p0 + px] = a;
    }
  }
}

// ---------------------------------------------------------------------------
// K4 (448 blocks): per-channel dyn-7x7 on fv + lepe-7x7 on x_skip, + bias.
// Block = (b, band of 8 rows, 8 channels). Zero-padded LDS stencil tiles.
// Thread = 2 consecutive px (224 active), 8-channel accumulators.
__global__ __launch_bounds__(256, 2) void k_mix(Params P){
  __shared__ float fvt[8][14][64];
  __shared__ float xst[8][14][64];
  __shared__ float w7l[8][49];
  __shared__ float b2l[8];
  float* W = P.W;
  const int tid = threadIdx.x;
  const int x = blockIdx.x, xcd = x & 7;
  const int b = xcd >> 1;
  const int u = (xcd & 1) + 2*(x >> 3);    // 0..111
  const int band = u % 7, chg = u / 7;
  const int c0 = chg*8, r0 = band*8;

  const int row = tid / 28, cp = tid % 28;
  const int col0 = cp*2;
  const int pxg = (r0 + row)*56 + col0;
  const bool act = tid < 224;

  float2 dr[49];
  if (act){
    #pragma unroll
    for (int k=0;k<49;++k)
      dr[k] = *(const float2*)(W + OFF_DYN + (size_t)(b*49+k)*HW + pxg);
  }

  for (int idx = tid; idx < 1792; idx += 256){
    const int cc = idx / 224, rem = idx % 224;
    const int rr = rem >> 4, cq = rem & 15;
    const int gr = r0 - 3 + rr, gcs = cq*4 - 4;
    float4 vf = {0.f,0.f,0.f,0.f}, vx = {0.f,0.f,0.f,0.f};
    if ((unsigned)gr < 56u){
      const size_t basef = OFF_FV + (size_t)(b*128 + c0 + cc)*HW + gr*56;
      const size_t basex = (size_t)(b*128 + c0 + cc)*HW + gr*56;
      if (gcs >= 0 && gcs + 3 < 56){
        vf = *(const float4*)(W + basef + gcs);
        vx = *(const float4*)(P.x_skip + basex + gcs);
      } else {
        float tf[4], tx[4];
        #pragma unroll
        for (int e=0;e<4;++e){
          const int gc = gcs + e;
          const bool v = (unsigned)gc < 56u;
          tf[e] = v ? W[basef + gc] : 0.f;
          tx[e] = v ? P.x_skip[basex + gc] : 0.f;
        }
        vf.x=tf[0];vf.y=tf[1];vf.z=tf[2];vf.w=tf[3];
        vx.x=tx[0];vx.y=tx[1];vx.z=tx[2];vx.w=tx[3];
      }
    }
    *(float4*)&fvt[cc][rr][cq*4] = vf;
    *(float4*)&xst[cc][rr][cq*4] = vx;
  }
  for (int idx = tid; idx < 392; idx += 256)
    w7l[idx/49][idx%49] = W[OFF_W7 + (c0 + idx/49)*49 + idx%49];
  if (tid < 8) b2l[tid] = W[OFF_BIAS + c0 + tid];
  __syncthreads();

  float a0[8], a1[8];
  if (act){
    #pragma unroll
    for (int c=0;c<8;++c){ a0[c] = b2l[c]; a1[c] = b2l[c]; }
    #pragma unroll
    for (int c=0;c<8;++c){
      #pragma unroll
      for (int i=0;i<7;++i){
        // window tile cols col0..col0+9 (b64-aligned, col0 even)
        const float2 f0 = *(const float2*)&fvt[c][row+i][col0];
        const float2 f1 = *(const float2*)&fvt[c][row+i][col0+2];
        const float2 f2 = *(const float2*)&fvt[c][row+i][col0+4];
        const float2 f3 = *(const float2*)&fvt[c][row+i][col0+6];
        const float2 f4 = *(const float2*)&fvt[c][row+i][col0+8];
        const float2 g0 = *(const float2*)&xst[c][row+i][col0];
        const float2 g1 = *(const float2*)&xst[c][row+i][col0+2];
        const float2 g2 = *(const float2*)&xst[c][row+i][col0+4];
        const float2 g3 = *(const float2*)&xst[c][row+i][col0+6];
        const float2 g4 = *(const float2*)&xst[c][row+i][col0+8];
        const float f[10] = {f0.x,f0.y,f1.x,f1.y,f2.x,f2.y,f3.x,f3.y,f4.x,f4.y};
        const float gg[10] = {g0.x,g0.y,g1.x,g1.y,g2.x,g2.y,g3.x,g3.y,g4.x,g4.y};
        #pragma unroll
        for (int j=0;j<7;++j){
          const float dx0 = dr[i*7+j].x, dx1 = dr[i*7+j].y;
          const float w7 = w7l[c][i*7+j];
          a0[c] += dx0 * f[1+j] + w7 * gg[1+j];
          a1[c] += dx1 * f[2+j] + w7 * gg[2+j];
        }
      }
    }
    #pragma unroll
    for (int c=0;c<8;++c){
      float2 v; v.x = a0[c]; v.y = a1[c];
      *(float2*)(W + OFF_XF + (size_t)(b*128 + c0 + c)*HW + pxg) = v;
    }
  }
  // channel-attention partials (wave reduce -> 1 atomic per wave per channel)
  #pragma unroll
  for (int c=0;c<8;++c){
    float s = act ? (a0[c] + a1[c]) : 0.f;
    float mm = act ? fmaxf(a0[c], a1[c]) : -1e30f;
    #pragma unroll
    for (int d=1; d<64; d<<=1){
      s += __shfl_xor(s, d, 64);
      mm = fmaxf(mm, __shfl_xor(mm, d, 64));
    }
    if ((tid & 63) == 0){
      atomicAdd(W + OFF_AVG + b*128 + c0 + c, s);
      atomicMax((u32*)W + OFF_MAXU + b*128 + c0 + c, fenc(mm));
    }
  }
}

// ---------------------------------------------------------------------------
// K5: channel-attention MLP, all batches (1 block, 512 threads).
__global__ __launch_bounds__(512) void k_ca(Params P){
  __shared__ float avl[512], mxl[512], hl[64];
  float* W = P.W;
  const int tid = threadIdx.x;
  avl[tid] = W[OFF_AVG + tid] * (1.f/3136.f);
  mxl[tid] = fdec(((u32*)W + OFF_MAXU)[tid]);
  __syncthreads();
  if (tid < 64){
    const int b = tid >> 4, which = (tid >> 3) & 1, r = tid & 7;
    const float* v = (which ? mxl : avl) + b*128;
    float a = 0.f;
    const float4* wr = (const float4*)(P.ca_w1 + r*128);
    for (int k0=0;k0<32;++k0){
      const float4 w4 = wr[k0];
      a += w4.x*v[k0*4] + w4.y*v[k0*4+1] + w4.z*v[k0*4+2] + w4.w*v[k0*4+3];
    }
    hl[tid] = fmaxf(a, 0.f);
  }
  __syncthreads();
  {
    const int b = tid >> 7, c = tid & 127;
    float a = 0.f;
    #pragma unroll
    for (int r=0;r<8;++r) a += P.ca_w2[c*8+r] * (hl[b*16+r] + hl[b*16+8+r]);
    W[OFF_CA + tid] = 1.f/(1.f + __expf(-a));
  }
}

// ---------------------------------------------------------------------------
// K6: streaming epilogue, grid (392,4).
__global__ __launch_bounds__(256) void k_final(Params P){
  float* W = P.W;
  const int tid = threadIdx.x;
  const int b = blockIdx.y;
  const int ofs = blockIdx.x*1024 + tid*4;
  const int c = ofs / 3136;
  const size_t gi = (size_t)b*401408 + ofs;
  const float ca = W[OFF_CA + b*128 + c];
  const float res = P.res[0];
  const float4 gv = *(const float4*)(W + OFF_GATE + gi);
  const float4 xv = *(const float4*)(W + OFF_XF + gi);
  const float4 sk = *(const float4*)(P.x_skip + gi);
  float4 ov;
  ov.x = gv.x*xv.x*ca + sk.x*res;
  ov.y = gv.y*xv.y*ca + sk.y*res;
  ov.z = gv.z*xv.z*ca + sk.z*res;
  ov.w = gv.w*xv.w*ca + sk.w*res;
  *(float4*)(P.out + gi) = ov;
}

// ---------------------------------------------------------------------------
extern "C" void kernel_launch(void* const* d_in, const int* in_sizes, int n_in,
                              void* d_out, int out_size, void* d_ws, size_t ws_size,
                              hipStream_t stream){
  Params P;
  const float* const* in = (const float* const*)d_in;
  P.x_up = in[0];  P.x_skip = in[1]; P.wq = in[2];  P.bq = in[3];
  P.wk = in[4];    P.bk = in[5];     P.wv = in[6];  P.bv = in[7];
  P.ww = in[8];    P.bw = in[9];
  P.lk_w = in[10]; P.lk_s = in[11];  P.lk_b = in[12];
  P.dw5 = in[13];  P.s5 = in[14];    P.b5 = in[15];
  P.dw3a = in[16]; P.s3a = in[17];   P.b3a = in[18];
  P.dw3b = in[19]; P.s3b = in[20];   P.b3b = in[21];
  P.dw3c = in[22]; P.s3c = in[23];   P.b3c = in[24];
  P.lepe_s = in[25]; P.lepe_b = in[26];
  P.gate_w = in[27]; P.gate_s = in[28]; P.gate_b = in[29];
  P.fus_w = in[30];  P.fus_b = in[31];
  P.ca_w1 = in[32];  P.ca_w2 = in[33]; P.res = in[34];
  P.W = (float*)d_ws;
  P.out = (float*)d_out;

  hipLaunchKernelGGL(k_prep,  dim3(194),   dim3(256), 0, stream, P);
  hipLaunchKernelGGL(k_key,   dim3(196),   dim3(128), 0, stream, P);
  hipLaunchKernelGGL(k_gemm,  dim3(392,2), dim3(256), 0, stream, P);
  hipLaunchKernelGGL(k_attn,  dim3(784),   dim3(256), 0, stream, P);
  hipLaunchKernelGGL(k_mix,   dim3(448),   dim3(256), 0, stream, P);
  hipLaunchKernelGGL(k_ca,    dim3(1),     dim3(512), 0, stream, P);
  hipLaunchKernelGGL(k_final, dim3(392,4), dim3(256), 0, stream, P);
}

// Round 8
// 268.779 us; speedup vs baseline: 1.5134x; 1.0566x over previous
//
#include <hip/hip_runtime.h>

typedef unsigned int u32;

#define HW 3136
#define SCALE 0.08838834764831843f   // 128^-0.5

// workspace offsets (float units)
#define OFF_W7    0        // 128*49 combined dw weights (lepe BN folded)
#define OFF_BIAS  6272     // 128: lepe folded bias + fus_b
#define OFF_POOL  6400     // 4*128*49 pooled x_up
#define OFF_MT    31488    // 4*128*49, Mt[b][k][l]
#define OFF_D     56576    // 4*49
#define OFF_AVG   56772    // 4*128
#define OFF_MAXU  57284    // 4*128 (encoded u32)
#define OFF_CA    57796    // 4*128
#define OFF_WC    58308    // 128*128 fus_w @ wv
#define OFF_BC    74692    // 128 fus_w @ bv
#define OFF_FV    74820    // 4*128*3136  fv = fus(value)
#define OFF_GATE  1680452  // 4*128*3136
#define OFF_DYN   3286084  // 4*49*3136
#define OFF_XF    3900740  // 4*128*3136

struct Params {
  const float *x_up, *x_skip, *wq, *bq, *wk, *bk, *wv, *bv, *ww, *bw;
  const float *lk_w, *lk_s, *lk_b, *dw5, *s5, *b5, *dw3a, *s3a, *b3a,
              *dw3b, *s3b, *b3b, *dw3c, *s3c, *b3c, *lepe_s, *lepe_b;
  const float *gate_w, *gate_s, *gate_b, *fus_w, *fus_b, *ca_w1, *ca_w2, *res;
  float* W;
  float* out;
};

__device__ __forceinline__ u32 fenc(float f){
  union{float f; u32 u;} v; v.f = f;
  return (v.u & 0x80000000u) ? ~v.u : (v.u | 0x80000000u);
}
__device__ __forceinline__ float fdec(u32 u){
  union{float f; u32 uu;} v;
  v.uu = (u & 0x80000000u) ? (u ^ 0x80000000u) : ~u;
  return v.f;
}

// ---------------------------------------------------------------------------
// K0 (grid 578): [0,512) pooling per (b,c); [512,576) Wc rows; 576 W7/bias/init;
// 577 bc.
__global__ __launch_bounds__(256) void k_prep(Params P){
  __shared__ float pl[3136];
  __shared__ float part[208];
  float* W = P.W;
  const int tid = threadIdx.x, blk = blockIdx.x;
  if (blk < 512){
    const int b = blk >> 7, c = blk & 127;
    const float* src = P.x_up + (size_t)(b*128 + c)*HW;
    for (int idx = tid; idx < 784; idx += 256)
      *(float4*)&pl[idx*4] = *(const float4*)(src + idx*4);
    __syncthreads();
    if (tid < 196){
      const int l = tid >> 2, s = tid & 3;
      const int i = l/7, j = l%7;
      float sm = 0.f;
      #pragma unroll
      for (int r=0;r<2;++r){
        const int base = (8*i + 2*s + r)*56 + 8*j;
        #pragma unroll
        for (int e=0;e<8;++e) sm += pl[base+e];
      }
      part[tid] = sm;
    }
    __syncthreads();
    if (tid < 49){
      const float sm = part[tid*4] + part[tid*4+1] + part[tid*4+2] + part[tid*4+3];
      W[OFF_POOL + (size_t)(b*128+c)*49 + tid] = sm * (1.f/64.f);
    }
  } else if (blk < 576){
    const int o = (blk - 512)*2 + (tid >> 7), c = tid & 127;
    float a = 0.f;
    #pragma unroll 8
    for (int m=0;m<128;++m) a += P.fus_w[o*128+m] * P.wv[m*128+c];
    W[OFF_WC + o*128 + c] = a;
  } else if (blk == 576){
    for (int idx = tid; idx < 6272; idx += 256){
      const int c = idx/49, k = idx%49;
      const int dy = k/7 - 3, dx = k%7 - 3;
      float w = P.lk_s[c] * P.lk_w[c*49 + k];
      if (dy>=-2 && dy<=2 && dx>=-2 && dx<=2)
        w += P.s5[c] * P.dw5[c*25 + (dy+2)*5 + (dx+2)];
      if (dy>=-1 && dy<=1 && dx>=-1 && dx<=1)
        w += P.s3a[c] * P.dw3a[c*9 + (dy+1)*3 + (dx+1)];
      if ((dy==-2||dy==0||dy==2) && (dx==-2||dx==0||dx==2))
        w += P.s3b[c] * P.dw3b[c*9 + (dy/2+1)*3 + (dx/2+1)];
      if ((dy==-3||dy==0||dy==3) && (dx==-3||dx==0||dx==3))
        w += P.s3c[c] * P.dw3c[c*9 + (dy/3+1)*3 + (dx/3+1)];
      W[OFF_W7 + idx] = P.lepe_s[c] * w;
    }
    if (tid < 128){
      const float bs = P.lk_b[tid] + P.b5[tid] + P.b3a[tid] + P.b3b[tid] + P.b3c[tid];
      W[OFF_BIAS + tid] = P.lepe_s[tid] * bs + P.lepe_b[tid] + P.fus_b[tid];
    }
    for (int i = tid; i < 512; i += 256){
      W[OFF_AVG + i] = 0.f;
      ((u32*)W + OFF_MAXU)[i] = fenc(-1e30f);
    }
  } else {
    if (tid < 128){
      float a = 0.f;
      #pragma unroll 8
      for (int m=0;m<128;++m) a += P.fus_w[tid*128+m] * P.bv[m];
      W[OFF_BC + tid] = a;
    }
  }
}

// ---------------------------------------------------------------------------
// K1 (196 x 128): key col -> Mt[b][k][l] (scaled), D[b][l].
__global__ __launch_bounds__(128) void k_key(Params P){
  __shared__ float pc[128], kc[128], red[128];
  float* W = P.W;
  const int b = blockIdx.x / 49, l = blockIdx.x % 49;
  const int t = threadIdx.x;
  pc[t] = W[OFF_POOL + (size_t)(b*128+t)*49 + l];
  __syncthreads();
  float acc = P.bk[t];
  const float4* wr = (const float4*)(P.wk + t*128);
  #pragma unroll 8
  for (int k0=0;k0<32;++k0){
    const float4 w = wr[k0];
    acc += w.x*pc[k0*4] + w.y*pc[k0*4+1] + w.z*pc[k0*4+2] + w.w*pc[k0*4+3];
  }
  kc[t] = acc;
  red[t] = P.bq[t] * acc;
  __syncthreads();
  float m = 0.f;
  #pragma unroll 8
  for (int c=0;c<128;++c) m += P.wq[c*128 + t] * kc[c];
  W[OFF_MT + (size_t)b*6272 + t*49 + l] = m * SCALE;
  if (t < 64) red[t] += red[t+64];
  __syncthreads();
  if (t < 32) red[t] += red[t+32];
  __syncthreads();
  if (t < 16) red[t] += red[t+16];
  __syncthreads();
  if (t < 8) red[t] += red[t+8];
  __syncthreads();
  if (t < 4) red[t] += red[t+4];
  __syncthreads();
  if (t == 0) W[OFF_D + b*49 + l] = (red[0]+red[1]+red[2]+red[3]) * SCALE;
}

// ---------------------------------------------------------------------------
// K2: fv / gate 1x1 conv, grid (784,2), strip 16. Thread = 2 outs x 4 px.
__global__ __launch_bounds__(256) void k_gemm(Params P){
  __shared__ float xl[128][20];
  __shared__ float wl[32][133];
  float* W = P.W;
  const int tid = threadIdx.x;
  const int x = blockIdx.x, xcd = x & 7;
  const int b = xcd >> 1;
  const int p0 = ((xcd & 1) + 2*(x >> 3)) * 16;
  const int mat = blockIdx.y;
  const float* __restrict__ wsrc = mat ? P.gate_w : (W + OFF_WC);

  for (int idx = tid; idx < 512; idx += 256){
    const int c = idx >> 2, pq = idx & 3;
    *(float4*)&xl[c][pq*4] =
        *(const float4*)(P.x_skip + (size_t)(b*128+c)*HW + p0 + pq*4);
  }

  const int oq = tid >> 2, pq = tid & 3;
  const int o0 = oq*2, px = pq*4;
  float i0 = 0.f, i1 = 0.f;
  if (mat == 0){ i0 = W[OFF_BC + o0]; i1 = W[OFF_BC + o0 + 1]; }
  float a0[4], a1[4];
  #pragma unroll
  for (int j=0;j<4;++j){ a0[j]=i0; a1[j]=i1; }

  for (int g=0; g<4; ++g){
    __syncthreads();
    for (int idx = tid; idx < 1024; idx += 256){
      const int o = idx >> 3, kq = idx & 7;
      const float4 v = *(const float4*)(wsrc + (size_t)o*128 + g*32 + kq*4);
      wl[kq*4+0][o] = v.x; wl[kq*4+1][o] = v.y;
      wl[kq*4+2][o] = v.z; wl[kq*4+3][o] = v.w;
    }
    __syncthreads();
    #pragma unroll 8
    for (int k=0;k<32;++k){
      const float2 w2 = *(const float2*)&wl[k][o0];
      const float4 x4 = *(const float4*)&xl[g*32+k][px];
      const float xv[4] = {x4.x,x4.y,x4.z,x4.w};
      #pragma unroll
      for (int j=0;j<4;++j){ a0[j] += w2.x*xv[j]; a1[j] += w2.y*xv[j]; }
    }
  }
  if (mat == 0){
    float4 v0 = {a0[0],a0[1],a0[2],a0[3]};
    float4 v1 = {a1[0],a1[1],a1[2],a1[3]};
    *(float4*)(W + OFF_FV + (size_t)(b*128+o0  )*HW + p0 + px) = v0;
    *(float4*)(W + OFF_FV + (size_t)(b*128+o0+1)*HW + p0 + px) = v1;
  } else {
    const float s0 = P.gate_s[o0], s1 = P.gate_s[o0+1];
    const float c0 = P.gate_b[o0], c1 = P.gate_b[o0+1];
    #pragma unroll
    for (int j=0;j<4;++j){
      float y0 = s0*a0[j] + c0, y1 = s1*a1[j] + c1;
      a0[j] = y0 / (1.f + __expf(-y0));
      a1[j] = y1 / (1.f + __expf(-y1));
    }
    float4 v0 = {a0[0],a0[1],a0[2],a0[3]};
    float4 v1 = {a1[0],a1[1],a1[2],a1[3]};
    *(float4*)(W + OFF_GATE + (size_t)(b*128+o0  )*HW + p0 + px) = v0;
    *(float4*)(W + OFF_GATE + (size_t)(b*128+o0+1)*HW + p0 + px) = v1;
  }
}

// ---------------------------------------------------------------------------
// K3 (784): logits = x^T Mt + D (LDS), softmax, dyn = ww@attn + bw.
__global__ __launch_bounds__(256) void k_attn(Params P){
  __shared__ float xl[128][16];
  __shared__ float mtl[6272];
  __shared__ float wwl[2401];
  __shared__ float attl[16][52];
  __shared__ float dvl[52];
  float* W = P.W;
  const int tid = threadIdx.x;
  const int x = blockIdx.x, xcd = x & 7;
  const int b = xcd >> 1;
  const int p0 = ((xcd & 1) + 2*(x >> 3)) * 16;

  for (int idx = tid; idx < 512; idx += 256){
    const int c = idx >> 2, pq = idx & 3;
    *(float4*)&xl[c][pq*4] =
        *(const float4*)(P.x_skip + (size_t)(b*128+c)*HW + p0 + pq*4);
  }
  for (int idx = tid; idx < 1568; idx += 256)
    *(float4*)&mtl[idx*4] = *(const float4*)(W + OFF_MT + (size_t)b*6272 + idx*4);
  for (int idx = tid; idx < 600; idx += 256)
    *(float4*)&wwl[idx*4] = *(const float4*)(P.ww + idx*4);
  if (tid == 0) wwl[2400] = P.ww[2400];
  if (tid < 49) dvl[tid] = W[OFF_D + b*49 + tid];
  __syncthreads();

  const int px = tid >> 4, sub = tid & 15;
  const int l0 = sub, l1 = sub+16, l2 = sub+32, l3 = sub+48;
  const int l3c = (l3 < 49) ? l3 : 48;
  float lv0 = dvl[l0], lv1 = dvl[l1], lv2 = dvl[l2];
  float lv3 = (l3 < 49) ? dvl[l3] : -1e30f;
  float a3 = 0.f;
  #pragma unroll 4
  for (int c=0;c<128;++c){
    const float xv = xl[c][px];
    lv0 += mtl[c*49+l0]*xv;
    lv1 += mtl[c*49+l1]*xv;
    lv2 += mtl[c*49+l2]*xv;
    a3  += mtl[c*49+l3c]*xv;
  }
  if (l3 < 49) lv3 += a3;

  float m = fmaxf(fmaxf(lv0, lv1), fmaxf(lv2, lv3));
  #pragma unroll
  for (int d=1; d<16; d<<=1) m = fmaxf(m, __shfl_xor(m, d, 64));
  const float e0 = __expf(lv0-m), e1 = __expf(lv1-m), e2 = __expf(lv2-m);
  const float e3 = (l3 < 49) ? __expf(lv3-m) : 0.f;
  float s = e0+e1+e2+e3;
  #pragma unroll
  for (int d=1; d<16; d<<=1) s += __shfl_xor(s, d, 64);
  const float inv = 1.f / s;
  attl[px][l0] = e0*inv;
  attl[px][l1] = e1*inv;
  attl[px][l2] = e2*inv;
  if (l3 < 49) attl[px][l3] = e3*inv;
  __syncthreads();

  #pragma unroll
  for (int j=0;j<4;++j){
    const int oo = sub + 16*j;
    if (oo < 49){
      float a = P.bw[oo];
      #pragma unroll 7
      for (int l=0;l<49;++l) a += wwl[oo*49+l] * attl[px][l];
      W[OFF_DYN + (size_t)(b*49+oo)*HW + p0 + px] = a;
    }
  }
}

// ---------------------------------------------------------------------------
// K4 (grid 1024): fused dyn-7x7 on fv + lepe-7x7 on x_skip + bias + CA.
// Block = (b, channel-pair, quarter of 14 rows). Thread = 4 px, 2 channels.
__global__ __launch_bounds__(256) void k_mix(Params P){
  __shared__ float fvs[2][20][64];
  __shared__ float xss[2][20][64];
  __shared__ float w7s[2][49];
  float* W = P.W;
  const int tid = threadIdx.x;
  const int blk = blockIdx.x, xcd = blk & 7;
  const int b = xcd >> 1;
  const int idx2 = blk >> 3;                  // 0..127
  const int cp = idx2 >> 1;                   // 0..63
  const int qt = (xcd & 1) + 2*(idx2 & 1);    // 0..3
  const int c0 = cp*2, r0 = qt*14;

  // stage fv & x_skip tiles (2 ch, rows r0-3..r0+16, cols -4..59, zero-pad)
  for (int idx = tid; idx < 1280; idx += 256){
    const int a2 = idx / 320;                  // 0..3
    const int ch = a2 & 1, arr = a2 >> 1;
    const int rem = idx % 320;
    const int rr = rem >> 4, cq = rem & 15;
    const int gr = r0 - 3 + rr, gc0 = cq*4 - 4;
    float4 v = {0.f,0.f,0.f,0.f};
    if ((unsigned)gr < 56u){
      const float* src = arr ? (P.x_skip + (size_t)(b*128 + c0 + ch)*HW + gr*56)
                             : (W + OFF_FV + (size_t)(b*128 + c0 + ch)*HW + gr*56);
      if (gc0 >= 0 && gc0 + 3 < 56){
        v = *(const float4*)(src + gc0);
      } else {
        float t[4];
        #pragma unroll
        for (int e=0;e<4;++e){
          const int gc = gc0 + e;
          t[e] = ((unsigned)gc < 56u) ? src[gc] : 0.f;
        }
        v.x=t[0]; v.y=t[1]; v.z=t[2]; v.w=t[3];
      }
    }
    if (arr) *(float4*)&xss[ch][rr][cq*4] = v;
    else     *(float4*)&fvs[ch][rr][cq*4] = v;
  }
  if (tid < 98) w7s[tid/49][tid%49] = W[OFF_W7 + (c0 + tid/49)*49 + tid%49];
  __syncthreads();

  const bool act = tid < 196;
  const int row = tid / 14, q = tid % 14;     // row 0..13, quad 0..13
  const int q4 = q*4;
  const int grow = r0 + row;
  float acc[2][4];
  {
    const float b0 = W[OFF_BIAS + c0], b1 = W[OFF_BIAS + c0 + 1];
    #pragma unroll
    for (int e=0;e<4;++e){ acc[0][e] = b0; acc[1][e] = b1; }
  }
  if (act){
    const float* dynb = W + OFF_DYN + (size_t)b*49*HW + grow*56 + q4;
    #pragma unroll
    for (int i=0;i<7;++i){
      float4 dr[7];
      #pragma unroll
      for (int j=0;j<7;++j)
        dr[j] = *(const float4*)(dynb + (size_t)(i*7+j)*HW);
      #pragma unroll
      for (int ch=0;ch<2;++ch){
        float fw[12], xw[12];
        {
          float4 t;
          t = *(const float4*)&fvs[ch][row+i][q4];    fw[0]=t.x;fw[1]=t.y;fw[2]=t.z;fw[3]=t.w;
          t = *(const float4*)&fvs[ch][row+i][q4+4];  fw[4]=t.x;fw[5]=t.y;fw[6]=t.z;fw[7]=t.w;
          t = *(const float4*)&fvs[ch][row+i][q4+8];  fw[8]=t.x;fw[9]=t.y;fw[10]=t.z;fw[11]=t.w;
          t = *(const float4*)&xss[ch][row+i][q4];    xw[0]=t.x;xw[1]=t.y;xw[2]=t.z;xw[3]=t.w;
          t = *(const float4*)&xss[ch][row+i][q4+4];  xw[4]=t.x;xw[5]=t.y;xw[6]=t.z;xw[7]=t.w;
          t = *(const float4*)&xss[ch][row+i][q4+8];  xw[8]=t.x;xw[9]=t.y;xw[10]=t.z;xw[11]=t.w;
        }
        #pragma unroll
        for (int j=0;j<7;++j){
          const float4 dv = dr[j];
          const float wv = w7s[ch][i*7+j];
          acc[ch][0] += dv.x*fw[j+1] + wv*xw[j+1];
          acc[ch][1] += dv.y*fw[j+2] + wv*xw[j+2];
          acc[ch][2] += dv.z*fw[j+3] + wv*xw[j+3];
          acc[ch][3] += dv.w*fw[j+4] + wv*xw[j+4];
        }
      }
    }
    #pragma unroll
    for (int ch=0;ch<2;++ch){
      float4 v = {acc[ch][0], acc[ch][1], acc[ch][2], acc[ch][3]};
      *(float4*)(W + OFF_XF + (size_t)(b*128 + c0 + ch)*HW + grow*56 + q4) = v;
    }
  }
  // channel-attention partials: wave reduce -> atomic per wave per channel
  #pragma unroll
  for (int ch=0;ch<2;++ch){
    float s = act ? (acc[ch][0]+acc[ch][1]+acc[ch][2]+acc[ch][3]) : 0.f;
    float mm = act ? fmaxf(fmaxf(acc[ch][0],acc[ch][1]),
                           fmaxf(acc[ch][2],acc[ch][3])) : -1e30f;
    #pragma unroll
    for (int d=1; d<64; d<<=1){
      s += __shfl_xor(s, d, 64);
      mm = fmaxf(mm, __shfl_xor(mm, d, 64));
    }
    if ((tid & 63) == 0){
      atomicAdd(W + OFF_AVG + b*128 + c0 + ch, s);
      atomicMax((u32*)W + OFF_MAXU + b*128 + c0 + ch, fenc(mm));
    }
  }
}

// ---------------------------------------------------------------------------
// K5: channel-attention MLP (1 block, 512 threads).
__global__ __launch_bounds__(512) void k_ca(Params P){
  __shared__ float avl[512], mxl[512], hl[64];
  float* W = P.W;
  const int tid = threadIdx.x;
  avl[tid] = W[OFF_AVG + tid] * (1.f/3136.f);
  mxl[tid] = fdec(((u32*)W + OFF_MAXU)[tid]);
  __syncthreads();
  if (tid < 64){
    const int b = tid >> 4, which = (tid >> 3) & 1, r = tid & 7;
    const float* v = (which ? mxl : avl) + b*128;
    float a = 0.f;
    const float4* wr = (const float4*)(P.ca_w1 + r*128);
    for (int k0=0;k0<32;++k0){
      const float4 w4 = wr[k0];
      a += w4.x*v[k0*4] + w4.y*v[k0*4+1] + w4.z*v[k0*4+2] + w4.w*v[k0*4+3];
    }
    hl[tid] = fmaxf(a, 0.f);
  }
  __syncthreads();
  {
    const int b = tid >> 7, c = tid & 127;
    float a = 0.f;
    #pragma unroll
    for (int r=0;r<8;++r) a += P.ca_w2[c*8+r] * (hl[b*16+r] + hl[b*16+8+r]);
    W[OFF_CA + tid] = 1.f/(1.f + __expf(-a));
  }
}

// ---------------------------------------------------------------------------
// K6: streaming epilogue, grid (392,4).
__global__ __launch_bounds__(256) void k_final(Params P){
  float* W = P.W;
  const int tid = threadIdx.x;
  const int b = blockIdx.y;
  const int ofs = blockIdx.x*1024 + tid*4;
  const int c = ofs / 3136;
  const size_t gi = (size_t)b*401408 + ofs;
  const float ca = W[OFF_CA + b*128 + c];
  const float res = P.res[0];
  const float4 gv = *(const float4*)(W + OFF_GATE + gi);
  const float4 xv = *(const float4*)(W + OFF_XF + gi);
  const float4 sk = *(const float4*)(P.x_skip + gi);
  float4 ov;
  ov.x = gv.x*xv.x*ca + sk.x*res;
  ov.y = gv.y*xv.y*ca + sk.y*res;
  ov.z = gv.z*xv.z*ca + sk.z*res;
  ov.w = gv.w*xv.w*ca + sk.w*res;
  *(float4*)(P.out + gi) = ov;
}

// ---------------------------------------------------------------------------
extern "C" void kernel_launch(void* const* d_in, const int* in_sizes, int n_in,
                              void* d_out, int out_size, void* d_ws, size_t ws_size,
                              hipStream_t stream){
  Params P;
  const float* const* in = (const float* const*)d_in;
  P.x_up = in[0];  P.x_skip = in[1]; P.wq = in[2];  P.bq = in[3];
  P.wk = in[4];    P.bk = in[5];     P.wv = in[6];  P.bv = in[7];
  P.ww = in[8];    P.bw = in[9];
  P.lk_w = in[10]; P.lk_s = in[11];  P.lk_b = in[12];
  P.dw5 = in[13];  P.s5 = in[14];    P.b5 = in[15];
  P.dw3a = in[16]; P.s3a = in[17];   P.b3a = in[18];
  P.dw3b = in[19]; P.s3b = in[20];   P.b3b = in[21];
  P.dw3c = in[22]; P.s3c = in[23];   P.b3c = in[24];
  P.lepe_s = in[25]; P.lepe_b = in[26];
  P.gate_w = in[27]; P.gate_s = in[28]; P.gate_b = in[29];
  P.fus_w = in[30];  P.fus_b = in[31];
  P.ca_w1 = in[32];  P.ca_w2 = in[33]; P.res = in[34];
  P.W = (float*)d_ws;
  P.out = (float*)d_out;

  hipLaunchKernelGGL(k_prep,  dim3(578),   dim3(256), 0, stream, P);
  hipLaunchKernelGGL(k_key,   dim3(196),   dim3(128), 0, stream, P);
  hipLaunchKernelGGL(k_gemm,  dim3(784,2), dim3(256), 0, stream, P);
  hipLaunchKernelGGL(k_attn,  dim3(784),   dim3(256), 0, stream, P);
  hipLaunchKernelGGL(k_mix,   dim3(1024),  dim3(256), 0, stream, P);
  hipLaunchKernelGGL(k_ca,    dim3(1),     dim3(512), 0, stream, P);
  hipLaunchKernelGGL(k_final, dim3(392,4), dim3(256), 0, stream, P);
}